// Round 2
// baseline (241.065 us; speedup 1.0000x reference)
//
#include <hip/hip_runtime.h>

// hashNeRF fused forward.
// Key structural facts exploited:
//  - The reference's hash is (ix ^ iy*2654435761) % 2 == parity(ix)^parity(iy),
//    and hash_table is indexed [hash, vertex, f] -> only HT[0:2, 0:4, 0:2]
//    (16 floats) are ever read. Encoding is pure VALU, no table traffic.
//  - Weights are wave-uniform with compile-time offsets -> compiler emits
//    s_load_dwordx16 + v_fmac_f32 (SGPR weight operand). No LDS needed.
//  - Layers 2 & 3 share one #pragma unroll 1 loop (uniform pointer select)
//    to halve code size: fully-unrolled body would exceed the 32KB L1I.
//  - All per-thread arrays are statically indexed (runtime-indexed register
//    arrays go to scratch on gfx950).

__global__ __launch_bounds__(256) void hashnerf_fused(
    const float* __restrict__ X,
    const float* __restrict__ HT,
    const float* __restrict__ W1, const float* __restrict__ B1,
    const float* __restrict__ W2, const float* __restrict__ B2,
    const float* __restrict__ W3, const float* __restrict__ B3,
    const float* __restrict__ W4, const float* __restrict__ B4,
    float* __restrict__ out, int npts)
{
    const int n = blockIdx.x * blockDim.x + threadIdx.x;
    if (n >= npts) return;

    const float2 xv = reinterpret_cast<const float2*>(X)[n];

    // t0[v*2+f] = HT[0][v][f], t1[v*2+f] = HT[1][v][f]; (L,T,F) layout, T*F=524288
    float t0[8], t1[8];
#pragma unroll
    for (int i = 0; i < 8; ++i) t0[i] = HT[i];
#pragma unroll
    for (int i = 0; i < 8; ++i) t1[i] = HT[524288 + i];

    // np.floor(np.float32(16.0 * (4^(1/15))**l)); l=15 rounds to exactly 64.0 in f32
    const float nvals[16] = {16.f,17.f,19.f,21.f,23.f,25.f,27.f,30.f,
                             33.f,36.f,40.f,44.f,48.f,53.f,58.f,64.f};

    float enc[32];
#pragma unroll
    for (int l = 0; l < 16; ++l) {
        const float sx = xv.x * nvals[l];
        const float sy = xv.y * nvals[l];
        const float fx = sx - floorf(sx);
        const float fy = sy - floorf(sy);
        const unsigned ix = (unsigned)sx;   // trunc == floor (x >= 0)
        const unsigned iy = (unsigned)sy;
        const bool px = (ix & 1u) != 0u;    // parity(ix)        (prime 1)
        const bool py = (iy & 1u) != 0u;    // parity(iy*odd) == parity(iy)
        const bool pz = px != py;
        const float cx = 1.0f - fx, cy = 1.0f - fy;
        const float w0 = cx * cy, w1 = cx * fy, w2 = fx * cy, w3 = fx * fy;
        // vertex hash: v0 -> 0, v1 -> py, v2 -> px, v3 -> px^py
        float a0 = w0 * t0[0];
        a0 = fmaf(w1, py ? t1[2] : t0[2], a0);
        a0 = fmaf(w2, px ? t1[4] : t0[4], a0);
        a0 = fmaf(w3, pz ? t1[6] : t0[6], a0);
        enc[2*l + 0] = a0;
        float a1 = w0 * t0[1];
        a1 = fmaf(w1, py ? t1[3] : t0[3], a1);
        a1 = fmaf(w2, px ? t1[5] : t0[5], a1);
        a1 = fmaf(w3, pz ? t1[7] : t0[7], a1);
        enc[2*l + 1] = a1;
    }

    // ---- layer 1: 32 -> 64, leaky relu -> ha ----
    float ha[64], hb[64];
#pragma unroll
    for (int j = 0; j < 64; ++j) hb[j] = B1[j];
#pragma unroll
    for (int k = 0; k < 32; ++k) {
        const float e = enc[k];
#pragma unroll
        for (int j = 0; j < 64; ++j) hb[j] = fmaf(e, W1[k*64 + j], hb[j]);
    }
#pragma unroll
    for (int j = 0; j < 64; ++j) ha[j] = fmaxf(hb[j], 0.01f * hb[j]);

    // ---- layers 2 & 3 (shared code, uniform pointer select): 64 -> 64, lrelu ----
#pragma unroll 1
    for (int layer = 0; layer < 2; ++layer) {
        const float* __restrict__ W = (layer == 0) ? W2 : W3;
        const float* __restrict__ B = (layer == 0) ? B2 : B3;
#pragma unroll
        for (int j = 0; j < 64; ++j) hb[j] = B[j];
#pragma unroll
        for (int k = 0; k < 64; ++k) {
            const float e = ha[k];
#pragma unroll
            for (int j = 0; j < 64; ++j) hb[j] = fmaf(e, W[k*64 + j], hb[j]);
        }
#pragma unroll
        for (int j = 0; j < 64; ++j) ha[j] = fmaxf(hb[j], 0.01f * hb[j]);  // lrelu doubles as ping-pong copy
    }

    // ---- layer 4: 64 -> 3, relu ----
    float o0 = B4[0], o1 = B4[1], o2 = B4[2];
#pragma unroll
    for (int k = 0; k < 64; ++k) {
        const float e = ha[k];
        o0 = fmaf(e, W4[k*3 + 0], o0);
        o1 = fmaf(e, W4[k*3 + 1], o1);
        o2 = fmaf(e, W4[k*3 + 2], o2);
    }
    out[n*3 + 0] = fmaxf(o0, 0.0f);
    out[n*3 + 1] = fmaxf(o1, 0.0f);
    out[n*3 + 2] = fmaxf(o2, 0.0f);
}

extern "C" void kernel_launch(void* const* d_in, const int* in_sizes, int n_in,
                              void* d_out, int out_size, void* d_ws, size_t ws_size,
                              hipStream_t stream) {
    const float* X  = (const float*)d_in[0];
    const float* HT = (const float*)d_in[1];
    const float* W1 = (const float*)d_in[2];
    const float* B1 = (const float*)d_in[3];
    const float* W2 = (const float*)d_in[4];
    const float* B2 = (const float*)d_in[5];
    const float* W3 = (const float*)d_in[6];
    const float* B3 = (const float*)d_in[7];
    const float* W4 = (const float*)d_in[8];
    const float* B4 = (const float*)d_in[9];
    float* out = (float*)d_out;

    const int npts = in_sizes[0] / 2;
    const int grid = (npts + 255) / 256;
    hipLaunchKernelGGL(hashnerf_fused, dim3(grid), dim3(256), 0, stream,
                       X, HT, W1, B1, W2, B2, W3, B3, W4, B4, out, npts);
}

// Round 4
// 155.085 us; speedup vs baseline: 1.5544x; 1.5544x over previous
//
#include <hip/hip_runtime.h>

// hashNeRF fused forward, MFMA edition.
//
// Facts carried from round 2 (absmax == 0.0 verified):
//  - hash == parity(ix) ^ parity(iy); only HT[0:2,0:4,0:2] (16 floats) ever read.
//  - encode formula below is bit-exact vs reference.
//
// MFMA scheme (v_mfma_f32_16x16x32_bf16, D = A(16x32)@B(32x16)+C):
//  - A = W^T fragments, VGPR-resident, loaded once per wave.
//      assumed A: row = lane&15, k = 8*(lane>>4)+e   (contiguous K)
//      assumed B: col = lane&15, k = 8*(lane>>4)+e
//      verified D: col = lane&15, row = 4*(lane>>4)+reg   [m89]
//  - B = activations for 16 points (point = lane&15).
//  - Precision: 3-product bf16 split (hi*hi + hi*lo + lo*hi) for L2/L3/L4.
//    L1 unsplit: inputs are O(1e-4) -> bf16 rel err 2^-9 is ~2e-6 absolute.
//  - Activations bounce through per-wave-private LDS H[16][68] (pad 68 spreads
//    banks uniformly; all accesses ds_*_b128). No __syncthreads in the loop:
//    DS ops within a wave execute in order (compiler inserts lgkmcnt waits).
//  - Biases staged in LDS, read as broadcast b128 quads into MFMA C-input.

typedef float  f32x4  __attribute__((ext_vector_type(4)));
typedef __bf16 bf16x8 __attribute__((ext_vector_type(8)));

#define MFMA16(A, B, C) __builtin_amdgcn_mfma_f32_16x16x32_bf16((A), (B), (C), 0, 0, 0)

__global__ __launch_bounds__(256) void hashnerf_mfma(
    const float* __restrict__ X,
    const float* __restrict__ HT,
    const float* __restrict__ W1, const float* __restrict__ B1,
    const float* __restrict__ W2, const float* __restrict__ B2,
    const float* __restrict__ W3, const float* __restrict__ B3,
    const float* __restrict__ W4, const float* __restrict__ B4,
    float* __restrict__ out, int npts)
{
    __shared__ __align__(16) float sBias[208];
    __shared__ __align__(16) float sH[4][16 * 68];

    const int tid = threadIdx.x;
    if (tid < 64) {
        sBias[tid]       = B1[tid];
        sBias[64 + tid]  = B2[tid];
        sBias[128 + tid] = B3[tid];
    }
    if (tid < 16) sBias[192 + tid] = (tid < 3) ? B4[tid] : 0.0f;
    __syncthreads();

    const int l  = tid & 63;
    const int p  = l & 15;      // point-in-tile (B/D col) and A-row base
    const int g  = l >> 4;      // lane group: K-chunk / D-row-quad selector
    const int wv = tid >> 6;
    float* __restrict__ Hw = sH[wv];

    // ---- one-time per-wave: weight fragments (A = W^T), hi/lo bf16 split ----
    bf16x8 w1h[4];                       // L1: 32->64, unsplit
#pragma unroll
    for (int t = 0; t < 4; ++t) {
#pragma unroll
        for (int e = 0; e < 8; ++e) {
            float w = W1[(8 * g + e) * 64 + p + 16 * t];
            w1h[t][e] = (__bf16)w;
        }
    }
    bf16x8 w2h[4][2], w2l[4][2], w3h[4][2], w3l[4][2];
#pragma unroll
    for (int t = 0; t < 4; ++t) {
#pragma unroll
        for (int s = 0; s < 2; ++s) {
#pragma unroll
            for (int e = 0; e < 8; ++e) {
                float w2 = W2[(32 * s + 8 * g + e) * 64 + p + 16 * t];
                __bf16 h2 = (__bf16)w2;
                w2h[t][s][e] = h2; w2l[t][s][e] = (__bf16)(w2 - (float)h2);
                float w3 = W3[(32 * s + 8 * g + e) * 64 + p + 16 * t];
                __bf16 h3 = (__bf16)w3;
                w3h[t][s][e] = h3; w3l[t][s][e] = (__bf16)(w3 - (float)h3);
            }
        }
    }
    bf16x8 w4h[2], w4l[2];               // L4: 64->3 (rows j>=3 zero)
#pragma unroll
    for (int s = 0; s < 2; ++s) {
#pragma unroll
        for (int e = 0; e < 8; ++e) {
            float w = (p < 3) ? W4[(32 * s + 8 * g + e) * 3 + p] : 0.0f;
            __bf16 h = (__bf16)w;
            w4h[s][e] = h; w4l[s][e] = (__bf16)(w - (float)h);
        }
    }

    // hash-table constants (the only 16 floats ever used)
    float t0[8], t1[8];
#pragma unroll
    for (int e = 0; e < 8; ++e) { t0[e] = HT[e]; t1[e] = HT[524288 + e]; }

    // this lane's 4 resolution levels (levels 4g..4g+3)
    const float NVA[4] = {16.f, 17.f, 19.f, 21.f};
    const float NVB[4] = {23.f, 25.f, 27.f, 30.f};
    const float NVC[4] = {33.f, 36.f, 40.f, 44.f};
    const float NVD[4] = {48.f, 53.f, 58.f, 64.f};
    float nv4[4];
#pragma unroll
    for (int j = 0; j < 4; ++j)
        nv4[j] = (g == 0) ? NVA[j] : (g == 1) ? NVB[j] : (g == 2) ? NVC[j] : NVD[j];

    // shared 64->64 layer (reads Hw, writes Hw; all reads precede all writes)
    auto mlp_layer = [&](const bf16x8 (&wh)[4][2], const bf16x8 (&wl)[4][2],
                         const float* __restrict__ bofs) {
        f32x4 a2[4];
#pragma unroll
        for (int t = 0; t < 4; ++t)
            a2[t] = *reinterpret_cast<const f32x4*>(&bofs[16 * t + 4 * g]);
#pragma unroll
        for (int s = 0; s < 2; ++s) {
            f32x4 q0 = *reinterpret_cast<const f32x4*>(&Hw[p * 68 + 32 * s + 8 * g]);
            f32x4 q1 = *reinterpret_cast<const f32x4*>(&Hw[p * 68 + 32 * s + 8 * g + 4]);
            bf16x8 xh, xl;
#pragma unroll
            for (int e = 0; e < 4; ++e) {
                __bf16 h0 = (__bf16)q0[e];
                xh[e] = h0;     xl[e] = (__bf16)(q0[e] - (float)h0);
                __bf16 h1 = (__bf16)q1[e];
                xh[4 + e] = h1; xl[4 + e] = (__bf16)(q1[e] - (float)h1);
            }
#pragma unroll
            for (int t = 0; t < 4; ++t) {
                a2[t] = MFMA16(wh[t][s], xh, a2[t]);
                a2[t] = MFMA16(wh[t][s], xl, a2[t]);
                a2[t] = MFMA16(wl[t][s], xh, a2[t]);
            }
        }
#pragma unroll
        for (int t = 0; t < 4; ++t) {
            f32x4 v = a2[t];
#pragma unroll
            for (int r = 0; r < 4; ++r) v[r] = fmaxf(v[r], 0.01f * v[r]);
            *reinterpret_cast<f32x4*>(&Hw[p * 68 + 16 * t + 4 * g]) = v;
        }
    };

    const int wave_global = blockIdx.x * 4 + wv;
    const int nwaves = gridDim.x * 4;
    const int ntiles = (npts + 15) >> 4;
    const float2* X2 = reinterpret_cast<const float2*>(X);

    for (int tile = wave_global; tile < ntiles; tile += nwaves) {
        const int pbase = tile << 4;
        const int pidx  = min(pbase + p, npts - 1);
        const float2 xv = X2[pidx];

        // ---- encode: this lane produces enc[8g..8g+7] of its point == its L1 B-frag ----
        bf16x8 bh;
#pragma unroll
        for (int j2 = 0; j2 < 4; ++j2) {
            const float nv = nv4[j2];
            const float sx = xv.x * nv, sy = xv.y * nv;
            const float fx = sx - floorf(sx), fy = sy - floorf(sy);
            const unsigned ix = (unsigned)sx, iy = (unsigned)sy;
            const bool px = (ix & 1u) != 0u, py = (iy & 1u) != 0u;
            const bool pz = px != py;
            const float cx = 1.f - fx, cy = 1.f - fy;
            const float q0 = cx * cy, q1 = cx * fy, q2 = fx * cy, q3 = fx * fy;
            float a0 = q0 * t0[0];
            a0 = fmaf(q1, py ? t1[2] : t0[2], a0);
            a0 = fmaf(q2, px ? t1[4] : t0[4], a0);
            a0 = fmaf(q3, pz ? t1[6] : t0[6], a0);
            float a1 = q0 * t0[1];
            a1 = fmaf(q1, py ? t1[3] : t0[3], a1);
            a1 = fmaf(q2, px ? t1[5] : t0[5], a1);
            a1 = fmaf(q3, pz ? t1[7] : t0[7], a1);
            bh[2 * j2]     = (__bf16)a0;
            bh[2 * j2 + 1] = (__bf16)a1;
        }

        // ---- L1: 32 -> 64 (unsplit), lrelu, -> LDS ----
        f32x4 acc[4];
#pragma unroll
        for (int t = 0; t < 4; ++t) {
            acc[t] = *reinterpret_cast<const f32x4*>(&sBias[16 * t + 4 * g]);
            acc[t] = MFMA16(w1h[t], bh, acc[t]);
        }
#pragma unroll
        for (int t = 0; t < 4; ++t) {
            f32x4 v = acc[t];
#pragma unroll
            for (int r = 0; r < 4; ++r) v[r] = fmaxf(v[r], 0.01f * v[r]);
            *reinterpret_cast<f32x4*>(&Hw[p * 68 + 16 * t + 4 * g]) = v;
        }

        // ---- L2, L3 ----
        mlp_layer(w2h, w2l, &sBias[64]);
        mlp_layer(w3h, w3l, &sBias[128]);

        // ---- L4: 64 -> 3 (split), relu, store ----
        f32x4 ao = *reinterpret_cast<const f32x4*>(&sBias[192 + 4 * g]);
#pragma unroll
        for (int s = 0; s < 2; ++s) {
            f32x4 q0 = *reinterpret_cast<const f32x4*>(&Hw[p * 68 + 32 * s + 8 * g]);
            f32x4 q1 = *reinterpret_cast<const f32x4*>(&Hw[p * 68 + 32 * s + 8 * g + 4]);
            bf16x8 xh, xl;
#pragma unroll
            for (int e = 0; e < 4; ++e) {
                __bf16 h0 = (__bf16)q0[e];
                xh[e] = h0;     xl[e] = (__bf16)(q0[e] - (float)h0);
                __bf16 h1 = (__bf16)q1[e];
                xh[4 + e] = h1; xl[4 + e] = (__bf16)(q1[e] - (float)h1);
            }
            ao = MFMA16(w4h[s], xh, ao);
            ao = MFMA16(w4h[s], xl, ao);
            ao = MFMA16(w4l[s], xh, ao);
        }
        if (g == 0 && pbase + p < npts) {
            float* op = out + (size_t)(pbase + p) * 3;
            op[0] = fmaxf(ao[0], 0.0f);
            op[1] = fmaxf(ao[1], 0.0f);
            op[2] = fmaxf(ao[2], 0.0f);
        }
    }
}

extern "C" void kernel_launch(void* const* d_in, const int* in_sizes, int n_in,
                              void* d_out, int out_size, void* d_ws, size_t ws_size,
                              hipStream_t stream) {
    const float* X  = (const float*)d_in[0];
    const float* HT = (const float*)d_in[1];
    const float* W1 = (const float*)d_in[2];
    const float* B1 = (const float*)d_in[3];
    const float* W2 = (const float*)d_in[4];
    const float* B2 = (const float*)d_in[5];
    const float* W3 = (const float*)d_in[6];
    const float* B3 = (const float*)d_in[7];
    const float* W4 = (const float*)d_in[8];
    const float* B4 = (const float*)d_in[9];
    float* out = (float*)d_out;

    const int npts = in_sizes[0] / 2;
    // 512 blocks x 4 waves = 2048 waves == one full residency round at 2 waves/SIMD;
    // 32768 tiles -> 16 tiles/wave, weight-fragment prologue amortized.
    hipLaunchKernelGGL(hashnerf_mfma, dim3(512), dim3(256), 0, stream,
                       X, HT, W1, B1, W2, B2, W3, B3, W4, B4, out, npts);
}